// Round 1
// baseline (3488.803 us; speedup 1.0000x reference)
//
#include <hip/hip_runtime.h>
#include <hip/hip_fp16.h>

#define ITERS 100

// -------- workspace layout (float units) --------
// r_part [2][16][16][128]  : 65536 floats   (row-sum partial slots, ping-pong)
// c_part [2][16][16][128]  : 65536          (col-sum partial slots)
// vs_part[2][16][16]       : 512            (per-col-stripe sum of v)
// us_part[2][16][16]       : 512            (per-row-stripe sum of u)
// fr     [2][16][16] (int) : 512            (row-exchange flags, value = it+1)
// fc     [2][16][16] (int) : 512            (col-exchange flags)
// total: 133120 floats = 520 KiB
#define WS_RPART 0
#define WS_CPART 65536
#define WS_VSP   131072
#define WS_USP   131584
#define WS_FR    132096
#define WS_FC    132608

__device__ __forceinline__ float wave_sum(float p) {
    p += __shfl_xor(p, 1, 64);
    p += __shfl_xor(p, 2, 64);
    p += __shfl_xor(p, 4, 64);
    p += __shfl_xor(p, 8, 64);
    p += __shfl_xor(p, 16, 64);
    p += __shfl_xor(p, 32, 64);
    return p;
}

__global__ void __launch_bounds__(256, 1)
sinkhorn_fused(const float* __restrict__ Q, const float* __restrict__ R,
               const float* __restrict__ zp, float* __restrict__ out,
               float* __restrict__ ws)
{
    // 64 KiB LDS, reused: GEMM staging first, then the two fp16 tile copies.
    __shared__ __align__(16) char smem[65536];
    float*  As  = (float*)smem;              // [2][32][128] k-major A slabs
    float*  Bs  = (float*)(smem + 32768);    // [2][32][128] k-major B slabs
    __half* Trm = (__half*)smem;             // [128][128] row-major K0 tile
    __half* Tcm = (__half*)(smem + 32768);   // [128][128] col-major, XOR-swizzled

    const int t   = threadIdx.x;
    const int b   = blockIdx.x;
    const int bi  = b >> 4, bj = b & 15;
    const int tx  = t & 15, ty = t >> 4;
    const int l   = t & 63, w  = t >> 6;
    const int gi0 = bi * 128, gj0 = bj * 128;

    // ---------------- phase 1: 128x128 score tile, fp32 GEMM K=512 ----------------
    float acc[8][8];
#pragma unroll
    for (int r = 0; r < 8; r++)
#pragma unroll
        for (int c = 0; c < 8; c++) acc[r][c] = 0.f;

    const int lr = t & 31, lc4 = t >> 5;   // staging: row-in-group 0..31, float4-col 0..7
    const float* Qb = Q + (size_t)gi0 * 512;
    const float* Rb = R + (size_t)gj0 * 512;

    float4 qa[4], ra[4];
#pragma unroll
    for (int i = 0; i < 4; i++) {          // slab 0 global->regs
        qa[i] = *(const float4*)(Qb + (size_t)(lr + 32 * i) * 512 + 4 * lc4);
        ra[i] = *(const float4*)(Rb + (size_t)(lr + 32 * i) * 512 + 4 * lc4);
    }
#pragma unroll
    for (int i = 0; i < 4; i++) {          // regs->LDS buf0 (k-major, conflict-free)
        int row = lr + 32 * i;
        As[(4*lc4+0)*128 + row] = qa[i].x;  As[(4*lc4+1)*128 + row] = qa[i].y;
        As[(4*lc4+2)*128 + row] = qa[i].z;  As[(4*lc4+3)*128 + row] = qa[i].w;
        Bs[(4*lc4+0)*128 + row] = ra[i].x;  Bs[(4*lc4+1)*128 + row] = ra[i].y;
        Bs[(4*lc4+2)*128 + row] = ra[i].z;  Bs[(4*lc4+3)*128 + row] = ra[i].w;
    }
    __syncthreads();

    for (int ks = 0; ks < 16; ks++) {
        if (ks < 15) {                      // prefetch next slab into regs
            int k0 = (ks + 1) * 32;
#pragma unroll
            for (int i = 0; i < 4; i++) {
                qa[i] = *(const float4*)(Qb + (size_t)(lr+32*i)*512 + k0 + 4*lc4);
                ra[i] = *(const float4*)(Rb + (size_t)(lr+32*i)*512 + k0 + 4*lc4);
            }
        }
        const float* A = As + (ks & 1) * (32 * 128);
        const float* B = Bs + (ks & 1) * (32 * 128);
#pragma unroll 4
        for (int k = 0; k < 32; k++) {
            float4 a0 = *(const float4*)(A + k*128 + 8*ty);
            float4 a1 = *(const float4*)(A + k*128 + 8*ty + 4);
            float4 b0 = *(const float4*)(B + k*128 + 8*tx);
            float4 b1 = *(const float4*)(B + k*128 + 8*tx + 4);
            float av[8] = {a0.x,a0.y,a0.z,a0.w,a1.x,a1.y,a1.z,a1.w};
            float bv[8] = {b0.x,b0.y,b0.z,b0.w,b1.x,b1.y,b1.z,b1.w};
#pragma unroll
            for (int r = 0; r < 8; r++)
#pragma unroll
                for (int c = 0; c < 8; c++)
                    acc[r][c] = fmaf(av[r], bv[c], acc[r][c]);
        }
        if (ks < 15) {
            __syncthreads();                // everyone done reading buf (ks+1)&1
            float* An = As + ((ks+1) & 1) * (32 * 128);
            float* Bn = Bs + ((ks+1) & 1) * (32 * 128);
#pragma unroll
            for (int i = 0; i < 4; i++) {
                int row = lr + 32 * i;
                An[(4*lc4+0)*128 + row] = qa[i].x;  An[(4*lc4+1)*128 + row] = qa[i].y;
                An[(4*lc4+2)*128 + row] = qa[i].z;  An[(4*lc4+3)*128 + row] = qa[i].w;
                Bn[(4*lc4+0)*128 + row] = ra[i].x;  Bn[(4*lc4+1)*128 + row] = ra[i].y;
                Bn[(4*lc4+2)*128 + row] = ra[i].z;  Bn[(4*lc4+3)*128 + row] = ra[i].w;
            }
            __syncthreads();
        }
    }
    __syncthreads();                        // As/Bs dead; LDS becomes Trm/Tcm

    // ---------------- phase 2: K0 = exp(score*10) -> fp16 tiles in LDS ----------------
    const float E = expf(zp[0] * 10.0f);    // augmented entry exp(z/eps)
#pragma unroll
    for (int r = 0; r < 8; r++) {
        int rr = 8 * ty + r;
        unsigned short hb[8];
#pragma unroll
        for (int c = 0; c < 8; c++) {
            float kv = expf(acc[r][c] * 10.0f);
            __half hh = __float2half(kv);
            hb[c] = __half_as_ushort(hh);
            int cc = 8 * tx + c;            // swizzle keeps b32 row-pairs adjacent,
            Tcm[cc * 128 + (rr ^ (2 * (cc & 63)))] = hh;  // banks conflict-free
        }
        uint4 pk;
        pk.x = hb[0] | ((unsigned)hb[1] << 16); pk.y = hb[2] | ((unsigned)hb[3] << 16);
        pk.z = hb[4] | ((unsigned)hb[5] << 16); pk.w = hb[6] | ((unsigned)hb[7] << 16);
        *(uint4*)&Trm[rr * 128 + 8 * tx] = pk;
    }
    __syncthreads();

    // ---------------- phase 3: 100 Sinkhorn iterations on u/v only ----------------
    float* r_part = ws + WS_RPART;
    float* c_part = ws + WS_CPART;
    float* vs_part = ws + WS_VSP;
    float* us_part = ws + WS_USP;
    int*   fr = (int*)(ws + WS_FR);
    int*   fc = (int*)(ws + WS_FC);

    float v0 = 1.f, v1 = 1.f, vN = 1.f, uN = 0.f;   // v for cols gj0+2l, gj0+2l+1
    float u0 = 1.f, u1 = 1.f;                        // u for rows gi0+2l, gi0+2l+1
    float vsum = 128.f;                              // sum of v over this col-stripe

    for (int it = 0; it < ITERS; it++) {
        const int buf = it & 1;
        const int slot = (buf * 16 + bi) * 16 + bj;

        // ---- u-phase: r_i = sum_j K0[i,j] v_j ----
        {
            float* rp = r_part + slot * 128;
#pragma unroll 4
            for (int rr2 = 0; rr2 < 32; rr2++) {
                int i = 32 * w + rr2;       // wave w handles rows 32w..32w+31
                __half2 h2 = *(const __half2*)&Trm[i * 128 + 2 * l];
                float2 kf = __half22float2(h2);
                float p = kf.x * v0 + kf.y * v1;
                p = wave_sum(p);
                if (l == 0) rp[i] = p;      // private slot: plain store, no atomics
            }
            if (t == 0) vs_part[slot] = vsum;
            __syncthreads();                // drains all waves' vmem (compiler waitcnt)
            if (t == 0)
                __hip_atomic_store(&fr[slot], it + 1, __ATOMIC_RELEASE, __HIP_MEMORY_SCOPE_AGENT);
            if (t < 16) {
                while (__hip_atomic_load(&fr[(buf * 16 + bi) * 16 + t],
                                         __ATOMIC_ACQUIRE, __HIP_MEMORY_SCOPE_AGENT) != it + 1)
                    __builtin_amdgcn_s_sleep(2);
            }
            __syncthreads();
            float r0 = 0.f, r1 = 0.f, vsall = 0.f;
#pragma unroll
            for (int s = 0; s < 16; s++) {
                float2 pr = *(const float2*)&r_part[((buf * 16 + bi) * 16 + s) * 128 + 2 * l];
                r0 += pr.x; r1 += pr.y;
            }
#pragma unroll
            for (int s = 0; s < 16; s++) vsall += vs_part[(buf * 16 + bi) * 16 + s];
            uN = 1.0f / (E * (vsall + vN)); // augmented row: all-E row, exact
            float EvN = E * vN;
            u0 = 1.0f / (r0 + EvN);
            u1 = 1.0f / (r1 + EvN);
        }
        float usum = wave_sum(u0 + u1);     // sum of u over this row-stripe

        // ---- v-phase: c_j = sum_i K0[i,j] u_i ----
        {
            float* cp = c_part + slot * 128;
            if (t == 0) us_part[slot] = usum;
#pragma unroll 4
            for (int cc2 = 0; cc2 < 32; cc2++) {
                int j = 32 * w + cc2;       // wave w handles cols 32w..32w+31
                __half2 h2 = *(const __half2*)&Tcm[j * 128 + ((2 * l) ^ (2 * (j & 63)))];
                float2 kf = __half22float2(h2);
                float p = kf.x * u0 + kf.y * u1;
                p = wave_sum(p);
                if (l == 0) cp[j] = p;
            }
            __syncthreads();
            if (t == 0)
                __hip_atomic_store(&fc[slot], it + 1, __ATOMIC_RELEASE, __HIP_MEMORY_SCOPE_AGENT);
            if (t < 16) {
                while (__hip_atomic_load(&fc[(buf * 16 + t) * 16 + bj],
                                         __ATOMIC_ACQUIRE, __HIP_MEMORY_SCOPE_AGENT) != it + 1)
                    __builtin_amdgcn_s_sleep(2);
            }
            __syncthreads();
            float c0 = 0.f, c1 = 0.f, usall = 0.f;
#pragma unroll
            for (int s = 0; s < 16; s++) {
                float2 pc = *(const float2*)&c_part[((buf * 16 + s) * 16 + bj) * 128 + 2 * l];
                c0 += pc.x; c1 += pc.y;
            }
#pragma unroll
            for (int s = 0; s < 16; s++) usall += us_part[(buf * 16 + s) * 16 + bj];
            vN = 1.0f / (E * (usall + uN)); // augmented col
            float EuN = E * uN;
            v0 = 1.0f / (c0 + EuN);
            v1 = 1.0f / (c1 + EuN);
        }
        vsum = wave_sum(v0 + v1);
    }

    // ---------------- phase 4: epilogue P = u_i K0 v_j, P_aug incl. augmented ----------------
    float* P  = out;                        // [2048][2048]
    float* PA = out + (size_t)2048 * 2048;  // [2049][2049]
#pragma unroll 2
    for (int rr2 = 0; rr2 < 32; rr2++) {
        int i = 32 * w + rr2;
        float usel = (i & 1) ? u1 : u0;
        float ui = __shfl(usel, i >> 1, 64);
        __half2 h2 = *(const __half2*)&Trm[i * 128 + 2 * l];
        float2 kf = __half22float2(h2);
        float p0 = ui * kf.x * v0;
        float p1 = ui * kf.y * v1;
        size_t gi = (size_t)(gi0 + i);
        *(float2*)&P[gi * 2048 + gj0 + 2 * l] = make_float2(p0, p1);
        PA[gi * 2049 + gj0 + 2 * l]     = p0;   // 2049 stride: only 4B-aligned
        PA[gi * 2049 + gj0 + 2 * l + 1] = p1;
        if (bj == 15 && l == 0) PA[gi * 2049 + 2048] = ui * E * vN;   // last col
    }
    if (bi == 15 && w == 0) {               // last row + corner
        PA[(size_t)2048 * 2049 + gj0 + 2 * l]     = uN * E * v0;
        PA[(size_t)2048 * 2049 + gj0 + 2 * l + 1] = uN * E * v1;
        if (bj == 15 && l == 0) PA[(size_t)2048 * 2049 + 2048] = uN * E * vN;
    }
}

extern "C" void kernel_launch(void* const* d_in, const int* in_sizes, int n_in,
                              void* d_out, int out_size, void* d_ws, size_t ws_size,
                              hipStream_t stream)
{
    (void)in_sizes; (void)n_in; (void)out_size; (void)ws_size;
    const float* Q  = (const float*)d_in[0];
    const float* R  = (const float*)d_in[1];
    const float* zp = (const float*)d_in[2];
    float* out = (float*)d_out;
    float* ws  = (float*)d_ws;
    void* args[] = { (void*)&Q, (void*)&R, (void*)&zp, (void*)&out, (void*)&ws };
    // 256 blocks == 256 CUs, 64 KiB LDS + <=256 VGPRs -> guaranteed co-resident.
    hipLaunchCooperativeKernel((const void*)sinkhorn_fused, dim3(256), dim3(256),
                               args, 0, stream);
}

// Round 2
// 1263.730 us; speedup vs baseline: 2.7607x; 2.7607x over previous
//
#include <hip/hip_runtime.h>
#include <hip/hip_fp16.h>

#define ITERS 100
#define AGENT __HIP_MEMORY_SCOPE_AGENT

// 8-byte message: fp32 value + iteration tag, moved as ONE relaxed agent-scope
// atomic (global_*_dwordx2 with sc0/sc1 -> coherent point, no buffer_inv/wbl2).
union PK { unsigned long long u; struct { float v; unsigned tag; } s; };

// ws layout (unsigned long long units):
//   rmsg[2][16][16][130] : row-stripe exchange, slot = [buf][bi][src_bj][0..127 row partials, 128 = src vsum]
//   cmsg[2][16][16][130] : col-stripe exchange, slot = [buf][bj][src_bi][0..127 col partials, 128 = src usum]
//   then per-block fp32 u/v scratch: 272 floats/block (ubuf[0..129], pad, vbuf at +136: [0..129])
#define MSG_SLOT 130
#define MSG_ONE  (2 * 16 * 16 * MSG_SLOT)     // one array, ulongs
#define UV_STRIDE 272

__device__ __forceinline__ float wave_sum(float p) {
    p += __shfl_xor(p, 1, 64);
    p += __shfl_xor(p, 2, 64);
    p += __shfl_xor(p, 4, 64);
    p += __shfl_xor(p, 8, 64);
    p += __shfl_xor(p, 16, 64);
    p += __shfl_xor(p, 32, 64);
    return p;
}

__global__ void __launch_bounds__(256, 1)
sinkhorn_fused(const float* __restrict__ Q, const float* __restrict__ R,
               const float* __restrict__ zp, float* __restrict__ out,
               unsigned long long* __restrict__ ws)
{
    // 64 KiB LDS. GEMM staging first, then the two fp16 tile copies.
    __shared__ __align__(16) char smem[65536];
    float* As = (float*)smem;               // [2][32][128] k-major A slabs
    float* Bs = (float*)(smem + 32768);     // [2][32][128] k-major B slabs
    char*  TrmB = smem;                     // [128 rows][16 chunks of 16B], chunk-swizzled
    char*  TcmB = smem + 32768;             // [128 cols][16 chunks of 16B], chunk-swizzled

    const int t  = threadIdx.x;
    const int b  = blockIdx.x;
    const int bi = b >> 4, bj = b & 15;
    const int tx = t & 15, ty = t >> 4;
    const int l  = t & 63, w  = t >> 6;
    const int gi0 = bi * 128, gj0 = bj * 128;

    // ---------------- phase 1: 128x128 score tile, fp32 GEMM K=512 ----------------
    float acc[8][8];
#pragma unroll
    for (int r = 0; r < 8; r++)
#pragma unroll
        for (int c = 0; c < 8; c++) acc[r][c] = 0.f;

    const int lr = t & 31, lc4 = t >> 5;
    const float* Qb = Q + (size_t)gi0 * 512;
    const float* Rb = R + (size_t)gj0 * 512;

    float4 qa[4], ra[4];
#pragma unroll
    for (int i = 0; i < 4; i++) {
        qa[i] = *(const float4*)(Qb + (size_t)(lr + 32 * i) * 512 + 4 * lc4);
        ra[i] = *(const float4*)(Rb + (size_t)(lr + 32 * i) * 512 + 4 * lc4);
    }
#pragma unroll
    for (int i = 0; i < 4; i++) {
        int row = lr + 32 * i;
        As[(4*lc4+0)*128 + row] = qa[i].x;  As[(4*lc4+1)*128 + row] = qa[i].y;
        As[(4*lc4+2)*128 + row] = qa[i].z;  As[(4*lc4+3)*128 + row] = qa[i].w;
        Bs[(4*lc4+0)*128 + row] = ra[i].x;  Bs[(4*lc4+1)*128 + row] = ra[i].y;
        Bs[(4*lc4+2)*128 + row] = ra[i].z;  Bs[(4*lc4+3)*128 + row] = ra[i].w;
    }
    __syncthreads();

    for (int ks = 0; ks < 16; ks++) {
        if (ks < 15) {
            int k0 = (ks + 1) * 32;
#pragma unroll
            for (int i = 0; i < 4; i++) {
                qa[i] = *(const float4*)(Qb + (size_t)(lr+32*i)*512 + k0 + 4*lc4);
                ra[i] = *(const float4*)(Rb + (size_t)(lr+32*i)*512 + k0 + 4*lc4);
            }
        }
        const float* A = As + (ks & 1) * (32 * 128);
        const float* B = Bs + (ks & 1) * (32 * 128);
#pragma unroll 4
        for (int k = 0; k < 32; k++) {
            float4 a0 = *(const float4*)(A + k*128 + 8*ty);
            float4 a1 = *(const float4*)(A + k*128 + 8*ty + 4);
            float4 b0 = *(const float4*)(B + k*128 + 8*tx);
            float4 b1 = *(const float4*)(B + k*128 + 8*tx + 4);
            float av[8] = {a0.x,a0.y,a0.z,a0.w,a1.x,a1.y,a1.z,a1.w};
            float bv[8] = {b0.x,b0.y,b0.z,b0.w,b1.x,b1.y,b1.z,b1.w};
#pragma unroll
            for (int r = 0; r < 8; r++)
#pragma unroll
                for (int c = 0; c < 8; c++)
                    acc[r][c] = fmaf(av[r], bv[c], acc[r][c]);
        }
        if (ks < 15) {
            __syncthreads();
            float* An = As + ((ks+1) & 1) * (32 * 128);
            float* Bn = Bs + ((ks+1) & 1) * (32 * 128);
#pragma unroll
            for (int i = 0; i < 4; i++) {
                int row = lr + 32 * i;
                An[(4*lc4+0)*128 + row] = qa[i].x;  An[(4*lc4+1)*128 + row] = qa[i].y;
                An[(4*lc4+2)*128 + row] = qa[i].z;  An[(4*lc4+3)*128 + row] = qa[i].w;
                Bn[(4*lc4+0)*128 + row] = ra[i].x;  Bn[(4*lc4+1)*128 + row] = ra[i].y;
                Bn[(4*lc4+2)*128 + row] = ra[i].z;  Bn[(4*lc4+3)*128 + row] = ra[i].w;
            }
            __syncthreads();
        }
    }
    __syncthreads();                        // As/Bs dead; LDS becomes Trm/Tcm

    // ---------------- phase 2: K0 = exp(score*10) -> swizzled fp16 tiles ----------------
    // Element (i,j): logical chunk c=j/8 stored at physical chunk c^(i&15)
    // (same scheme for the col-major copy) -> matvec b128 reads are <=2-way.
    const float E = expf(zp[0] * 10.0f);
#pragma unroll
    for (int r = 0; r < 8; r++)
#pragma unroll
        for (int c = 0; c < 8; c++) acc[r][c] = expf(acc[r][c] * 10.0f);

#pragma unroll
    for (int r = 0; r < 8; r++) {           // row-major tile: one 16B chunk per row
        int rr = 8 * ty + r;
        unsigned short h[8];
#pragma unroll
        for (int c = 0; c < 8; c++) h[c] = __half_as_ushort(__float2half(acc[r][c]));
        uint4 pk;
        pk.x = h[0] | ((unsigned)h[1] << 16); pk.y = h[2] | ((unsigned)h[3] << 16);
        pk.z = h[4] | ((unsigned)h[5] << 16); pk.w = h[6] | ((unsigned)h[7] << 16);
        *(uint4*)(TrmB + rr * 256 + ((tx ^ (rr & 15)) << 4)) = pk;
    }
#pragma unroll
    for (int c = 0; c < 8; c++) {           // col-major tile
        int cc = 8 * tx + c;
        unsigned short h[8];
#pragma unroll
        for (int r = 0; r < 8; r++) h[r] = __half_as_ushort(__float2half(acc[r][c]));
        uint4 pk;
        pk.x = h[0] | ((unsigned)h[1] << 16); pk.y = h[2] | ((unsigned)h[3] << 16);
        pk.z = h[4] | ((unsigned)h[5] << 16); pk.w = h[6] | ((unsigned)h[7] << 16);
        *(uint4*)(TcmB + cc * 256 + ((ty ^ (cc & 15)) << 4)) = pk;
    }

    // ---------------- scratch pointers + init ----------------
    unsigned long long* rmsg = ws;
    unsigned long long* cmsg = ws + MSG_ONE;
    float* uvb  = (float*)(ws + 2 * MSG_ONE) + b * UV_STRIDE;
    float* ubuf = uvb;                      // [0..127] u, [128..129] wave partial sums
    float* vbuf = uvb + 136;                // [0..127] v, [128..129] wave partial sums

    if (t < 128)      vbuf[t] = 1.0f;
    else if (t < 130) vbuf[t] = 64.0f;      // so vbuf[128]+vbuf[129] = 128 = initial vsum
    float uN = 0.f, vN = 1.0f, vsum = 128.0f, usum = 0.f;
    __syncthreads();                        // tiles + vbuf ready

    // ---------------- phase 3: 100 Sinkhorn iterations ----------------
    for (int it = 0; it < ITERS; it++) {
        const int buf = it & 1;
        const unsigned tagw = (unsigned)(it + 1);

        // ======== u-phase: r_i = sum_j K[i,j] v_j ========
        {
            unsigned long long* base = rmsg + (size_t)((buf * 16 + bi) * 16) * MSG_SLOT;
            if (t < 128) {
                const char* rp = TrmB + t * 256;
                const float4* v4 = (const float4*)vbuf;
                float racc = 0.f;
#pragma unroll
                for (int c = 0; c < 16; c++) {
                    uint4 kq = *(const uint4*)(rp + ((c ^ (t & 15)) << 4));
                    float4 va = v4[2 * c], vb = v4[2 * c + 1];
                    const __half2* h2 = (const __half2*)&kq;
                    float2 f;
                    f = __half22float2(h2[0]); racc = fmaf(f.x, va.x, fmaf(f.y, va.y, racc));
                    f = __half22float2(h2[1]); racc = fmaf(f.x, va.z, fmaf(f.y, va.w, racc));
                    f = __half22float2(h2[2]); racc = fmaf(f.x, vb.x, fmaf(f.y, vb.y, racc));
                    f = __half22float2(h2[3]); racc = fmaf(f.x, vb.z, fmaf(f.y, vb.w, racc));
                }
                PK p; p.s.v = racc; p.s.tag = tagw;
                __hip_atomic_store(base + (size_t)bj * MSG_SLOT + t, p.u, __ATOMIC_RELAXED, AGENT);
            } else if (t == 128) {
                PK p; p.s.v = vsum; p.s.tag = tagw;
                __hip_atomic_store(base + (size_t)bj * MSG_SLOT + 128, p.u, __ATOMIC_RELAXED, AGENT);
            }
            // parallel poll: 16 element slots (t<128) + 16 stripe-vsum slots (all)
            unsigned em = (t < 128) ? 0xFFFFu : 0u;
            unsigned sm = 0xFFFFu;
            float rsum = 0.f, ssum = 0.f;
            while (em | sm) {
                unsigned long long ev[16], sv[16];
#pragma unroll
                for (int s = 0; s < 16; s++) if ((em >> s) & 1)
                    ev[s] = __hip_atomic_load(base + (size_t)s * MSG_SLOT + t, __ATOMIC_RELAXED, AGENT);
#pragma unroll
                for (int s = 0; s < 16; s++) if ((sm >> s) & 1)
                    sv[s] = __hip_atomic_load(base + (size_t)s * MSG_SLOT + 128, __ATOMIC_RELAXED, AGENT);
#pragma unroll
                for (int s = 0; s < 16; s++) if ((em >> s) & 1) {
                    PK p; p.u = ev[s];
                    if (p.s.tag == tagw) { rsum += p.s.v; em &= ~(1u << s); }
                }
#pragma unroll
                for (int s = 0; s < 16; s++) if ((sm >> s) & 1) {
                    PK p; p.u = sv[s];
                    if (p.s.tag == tagw) { ssum += p.s.v; sm &= ~(1u << s); }
                }
                if (em | sm) __builtin_amdgcn_s_sleep(1);
            }
            float nuN = 1.0f / (E * (ssum + vN));   // augmented all-E row, exact
            if (t < 128) {
                float ui = 1.0f / (rsum + E * vN);
                ubuf[t] = ui;
                float wsm = wave_sum(ui);           // once per phase, off critical LDS path
                if (l == 0) ubuf[128 + w] = wsm;
            }
            uN = nuN;
            __syncthreads();                        // ubuf complete
            usum = ubuf[128] + ubuf[129];           // this row-stripe's sum of u
        }

        // ======== v-phase: c_j = sum_i K[i,j] u_i ========
        {
            unsigned long long* base = cmsg + (size_t)((buf * 16 + bj) * 16) * MSG_SLOT;
            if (t < 128) {
                const char* cp = TcmB + t * 256;
                const float4* u4 = (const float4*)ubuf;
                float cacc = 0.f;
#pragma unroll
                for (int c = 0; c < 16; c++) {
                    uint4 kq = *(const uint4*)(cp + ((c ^ (t & 15)) << 4));
                    float4 ua = u4[2 * c], ub = u4[2 * c + 1];
                    const __half2* h2 = (const __half2*)&kq;
                    float2 f;
                    f = __half22float2(h2[0]); cacc = fmaf(f.x, ua.x, fmaf(f.y, ua.y, cacc));
                    f = __half22float2(h2[1]); cacc = fmaf(f.x, ua.z, fmaf(f.y, ua.w, cacc));
                    f = __half22float2(h2[2]); cacc = fmaf(f.x, ub.x, fmaf(f.y, ub.y, cacc));
                    f = __half22float2(h2[3]); cacc = fmaf(f.x, ub.z, fmaf(f.y, ub.w, cacc));
                }
                PK p; p.s.v = cacc; p.s.tag = tagw;
                __hip_atomic_store(base + (size_t)bi * MSG_SLOT + t, p.u, __ATOMIC_RELAXED, AGENT);
            } else if (t == 128) {
                PK p; p.s.v = usum; p.s.tag = tagw;
                __hip_atomic_store(base + (size_t)bi * MSG_SLOT + 128, p.u, __ATOMIC_RELAXED, AGENT);
            }
            unsigned em = (t < 128) ? 0xFFFFu : 0u;
            unsigned sm = 0xFFFFu;
            float csum = 0.f, ssum = 0.f;
            while (em | sm) {
                unsigned long long ev[16], sv[16];
#pragma unroll
                for (int s = 0; s < 16; s++) if ((em >> s) & 1)
                    ev[s] = __hip_atomic_load(base + (size_t)s * MSG_SLOT + t, __ATOMIC_RELAXED, AGENT);
#pragma unroll
                for (int s = 0; s < 16; s++) if ((sm >> s) & 1)
                    sv[s] = __hip_atomic_load(base + (size_t)s * MSG_SLOT + 128, __ATOMIC_RELAXED, AGENT);
#pragma unroll
                for (int s = 0; s < 16; s++) if ((em >> s) & 1) {
                    PK p; p.u = ev[s];
                    if (p.s.tag == tagw) { csum += p.s.v; em &= ~(1u << s); }
                }
#pragma unroll
                for (int s = 0; s < 16; s++) if ((sm >> s) & 1) {
                    PK p; p.u = sv[s];
                    if (p.s.tag == tagw) { ssum += p.s.v; sm &= ~(1u << s); }
                }
                if (em | sm) __builtin_amdgcn_s_sleep(1);
            }
            float nvN = 1.0f / (E * (ssum + uN));   // augmented all-E col
            if (t < 128) {
                float vj = 1.0f / (csum + E * uN);
                vbuf[t] = vj;
                float wsm = wave_sum(vj);
                if (l == 0) vbuf[128 + w] = wsm;
            }
            vN = nvN;
            __syncthreads();                        // vbuf complete
            vsum = vbuf[128] + vbuf[129];           // this col-stripe's sum of v
        }
    }

    // ---------------- phase 4: epilogue P = u_i K0 v_j ----------------
    float* P  = out;                        // [2048][2048]
    float* PA = out + (size_t)2048 * 2048;  // [2049][2049]
    float2 vv = *(const float2*)&vbuf[2 * l];   // this lane's two columns
#pragma unroll 2
    for (int rr2 = 0; rr2 < 32; rr2++) {
        int i = 32 * w + rr2;
        float ui = ubuf[i];
        const char* rp = TrmB + i * 256;
        int c = l >> 2;                     // logical chunk of col 2l
        __half2 h2 = *(const __half2*)(rp + ((c ^ (i & 15)) << 4) + (l & 3) * 4);
        float2 kf = __half22float2(h2);
        float p0 = ui * kf.x * vv.x;
        float p1 = ui * kf.y * vv.y;
        size_t gi = (size_t)(gi0 + i);
        *(float2*)&P[gi * 2048 + gj0 + 2 * l] = make_float2(p0, p1);
        PA[gi * 2049 + gj0 + 2 * l]     = p0;
        PA[gi * 2049 + gj0 + 2 * l + 1] = p1;
        if (bj == 15 && l == 0) PA[gi * 2049 + 2048] = ui * E * vN;     // last col
    }
    if (bi == 15 && w == 0) {               // last row + corner
        PA[(size_t)2048 * 2049 + gj0 + 2 * l]     = uN * E * vv.x;
        PA[(size_t)2048 * 2049 + gj0 + 2 * l + 1] = uN * E * vv.y;
        if (bj == 15 && l == 0) PA[(size_t)2048 * 2049 + 2048] = uN * E * vN;
    }
}

extern "C" void kernel_launch(void* const* d_in, const int* in_sizes, int n_in,
                              void* d_out, int out_size, void* d_ws, size_t ws_size,
                              hipStream_t stream)
{
    (void)in_sizes; (void)n_in; (void)out_size; (void)ws_size;
    const float* Q  = (const float*)d_in[0];
    const float* R  = (const float*)d_in[1];
    const float* zp = (const float*)d_in[2];
    float* out = (float*)d_out;
    unsigned long long* ws = (unsigned long long*)d_ws;
    void* args[] = { (void*)&Q, (void*)&R, (void*)&zp, (void*)&out, (void*)&ws };
    // 256 blocks == 256 CUs, 64 KiB LDS, 1 block/CU -> co-resident for spin-wait.
    hipLaunchCooperativeKernel((const void*)sinkhorn_fused, dim3(256), dim3(256),
                               args, 0, stream);
}